// Round 2
// baseline (147.128 us; speedup 1.0000x reference)
//
#include <hip/hip_runtime.h>
#include <math.h>

#define N_ATOMS 8192
#define NGRAPH  32
#define HDIM    64
#define KTOT    728
#define TWO_PI  6.28318530717958647692f

__device__ __forceinline__ float silu_f(float x) {
    return x / (1.0f + expf(-x));
}

// ---------------- Kernel A: per-graph inverse + per-k MLP weight ----------------
__global__ __launch_bounds__(256) void kA(
    const float* __restrict__ cell,
    const float* __restrict__ W1, const float* __restrict__ b1,
    const float* __restrict__ W2, const float* __restrict__ b2,
    const float* __restrict__ W3, const float* __restrict__ b3,
    float* __restrict__ inv_out, float* __restrict__ wout)
{
    int b = blockIdx.x;
    int k = blockIdx.y * 256 + threadIdx.x;

    const float* cb = cell + b * 9;
    float a00 = cb[0], a01 = cb[1], a02 = cb[2];
    float a10 = cb[3], a11 = cb[4], a12 = cb[5];
    float a20 = cb[6], a21 = cb[7], a22 = cb[8];

    float c00 = a11 * a22 - a12 * a21;
    float c01 = a12 * a20 - a10 * a22;
    float c02 = a10 * a21 - a11 * a20;
    float det = a00 * c00 + a01 * c01 + a02 * c02;
    float vol = fmaxf(fabsf(det), 1e-6f);
    float rdet = 1.0f / det;

    float inv00 = c00 * rdet;
    float inv01 = (a02 * a21 - a01 * a22) * rdet;
    float inv02 = (a01 * a12 - a02 * a11) * rdet;
    float inv10 = c01 * rdet;
    float inv11 = (a00 * a22 - a02 * a20) * rdet;
    float inv12 = (a02 * a10 - a00 * a12) * rdet;
    float inv20 = c02 * rdet;
    float inv21 = (a01 * a20 - a00 * a21) * rdet;
    float inv22 = (a00 * a11 - a01 * a10) * rdet;

    if (blockIdx.y == 0 && threadIdx.x == 0) {
        float* iv = inv_out + b * 9;
        iv[0] = inv00; iv[1] = inv01; iv[2] = inv02;
        iv[3] = inv10; iv[4] = inv11; iv[5] = inv12;
        iv[6] = inv20; iv[7] = inv21; iv[8] = inv22;
    }

    if (k >= KTOT) return;

    int idx = (k < 364) ? k : k + 1;   // skip the (0,0,0) lattice point
    int ii = idx / 81 - 4;
    int jj = (idx / 9) % 9 - 4;
    int ll = idx % 9 - 4;
    float fi = (float)ii, fj = (float)jj, fl = (float)ll;

    float kx = TWO_PI * (fi * inv00 + fj * inv10 + fl * inv20);
    float ky = TWO_PI * (fi * inv01 + fj * inv11 + fl * inv21);
    float kz = TWO_PI * (fi * inv02 + fj * inv12 + fl * inv22);
    float kn = sqrtf(kx * kx + ky * ky + kz * kz);
    float sk = fmaxf(kn, 1e-6f);

    float x0 = log1pf(sk);
    float f0 = x0, f1 = x0 * x0, f2 = 1.0f / sk;

    float h1v[HDIM];
    #pragma unroll
    for (int j = 0; j < HDIM; ++j) {
        float a = b1[j] + f0 * W1[j] + f1 * W1[64 + j] + f2 * W1[128 + j];
        h1v[j] = silu_f(a);
    }

    float out = b3[0];
    for (int half = 0; half < 2; ++half) {
        float acc[32];
        #pragma unroll
        for (int j = 0; j < 32; ++j) acc[j] = b2[half * 32 + j];
        for (int i = 0; i < HDIM; ++i) {
            float h = h1v[i];
            const float* w2row = W2 + i * 64 + half * 32;
            #pragma unroll
            for (int j = 0; j < 32; ++j) acc[j] = fmaf(h, w2row[j], acc[j]);
        }
        #pragma unroll
        for (int j = 0; j < 32; ++j) out += silu_f(acc[j]) * W3[half * 32 + j];
    }

    float sc = (out > 20.0f) ? out : log1pf(expf(out));
    float w = (12.566370614359172954f / (sk * sk)) * sc;  // 4*pi / k^2 * scale
    if (!(kn > 1e-6f)) w = 0.0f;
    wout[b * KTOT + k] = w / (2.0f * vol);                // fold 0.5/vol epilogue
}

// ---------------- graph start offsets (batch is sorted) ----------------
__global__ void kStart(const int* __restrict__ batch, int* __restrict__ start)
{
    int t = threadIdx.x;
    if (t > NGRAPH) return;
    int lo = 0, hi = N_ATOMS;
    while (lo < hi) {
        int mid = (lo + hi) >> 1;
        if (batch[mid] < t) lo = mid + 1; else hi = mid;
    }
    start[t] = lo;
}

// ---------------- 2*pi * fractional coords ----------------
__global__ __launch_bounds__(256) void kFrac(
    const float* __restrict__ pos, const int* __restrict__ batch,
    const float* __restrict__ inv, float* __restrict__ frac2pi)
{
    int n = blockIdx.x * 256 + threadIdx.x;
    if (n >= N_ATOMS) return;
    int b = batch[n];
    const float* iv = inv + b * 9;
    float px = pos[n * 3], py = pos[n * 3 + 1], pz = pos[n * 3 + 2];
    frac2pi[n * 3 + 0] = TWO_PI * (px * iv[0] + py * iv[3] + pz * iv[6]);
    frac2pi[n * 3 + 1] = TWO_PI * (px * iv[1] + py * iv[4] + pz * iv[7]);
    frac2pi[n * 3 + 2] = TWO_PI * (px * iv[2] + py * iv[5] + pz * iv[8]);
}

// ---------------- Kernel B: structure factors ----------------
#define CHUNK 64
__global__ __launch_bounds__(256) void kS(
    const float* __restrict__ frac2pi, const float* __restrict__ source,
    const int* __restrict__ start,
    float* __restrict__ Sc, float* __restrict__ Ss)
{
    __shared__ float2 tab[CHUNK][3][9];   // cos/sin(m * p_d), m in [-4,4]
    __shared__ float4 srcs[CHUNK];

    int b = blockIdx.x;
    int tid = threadIdx.x;
    int k = blockIdx.y * 256 + tid;

    int s0 = start[b], e0 = start[b + 1];
    int len = e0 - s0;
    int per = (len + 3) >> 2;             // gridDim.z == 4 atom slices
    int nb = s0 + blockIdx.z * per;
    int ne = min(nb + per, e0);

    bool active = (k < KTOT);
    int kk = active ? k : 0;
    int idx = (kk < 364) ? kk : kk + 1;
    int ip4 = idx / 81;
    int jp4 = (idx / 9) % 9;
    int lp4 = idx % 9;

    float4 accC = make_float4(0.f, 0.f, 0.f, 0.f);
    float4 accS = make_float4(0.f, 0.f, 0.f, 0.f);

    for (int base = nb; base < ne; base += CHUNK) {
        int cnt = min(CHUNK, ne - base);
        __syncthreads();
        if (tid < 192) {
            int a = tid & 63, d = tid >> 6;
            if (a < cnt) {
                float p = frac2pi[(base + a) * 3 + d];
                float s1, c1; sincosf(p, &s1, &c1);
                float c2 = c1 * c1 - s1 * s1, s2 = 2.f * c1 * s1;
                float c3 = c2 * c1 - s2 * s1, s3 = c2 * s1 + s2 * c1;
                float c4 = c2 * c2 - s2 * s2, s4 = 2.f * c2 * s2;
                tab[a][d][4] = make_float2(1.f, 0.f);
                tab[a][d][5] = make_float2(c1, s1);
                tab[a][d][3] = make_float2(c1, -s1);
                tab[a][d][6] = make_float2(c2, s2);
                tab[a][d][2] = make_float2(c2, -s2);
                tab[a][d][7] = make_float2(c3, s3);
                tab[a][d][1] = make_float2(c3, -s3);
                tab[a][d][8] = make_float2(c4, s4);
                tab[a][d][0] = make_float2(c4, -s4);
            }
        } else {
            int a = tid - 192;
            if (a < cnt) srcs[a] = ((const float4*)source)[base + a];
        }
        __syncthreads();

        if (active) {
            for (int a = 0; a < cnt; ++a) {
                float2 ti = tab[a][0][ip4];
                float2 tj = tab[a][1][jp4];
                float2 tl = tab[a][2][lp4];
                float c12 = ti.x * tj.x - ti.y * tj.y;
                float s12 = ti.x * tj.y + ti.y * tj.x;
                float cv = c12 * tl.x - s12 * tl.y;
                float sv = c12 * tl.y + s12 * tl.x;
                float4 s = srcs[a];
                accC.x = fmaf(s.x, cv, accC.x); accC.y = fmaf(s.y, cv, accC.y);
                accC.z = fmaf(s.z, cv, accC.z); accC.w = fmaf(s.w, cv, accC.w);
                accS.x = fmaf(s.x, sv, accS.x); accS.y = fmaf(s.y, sv, accS.y);
                accS.z = fmaf(s.z, sv, accS.z); accS.w = fmaf(s.w, sv, accS.w);
            }
        }
    }

    if (active) {
        float* pc = Sc + (size_t)(b * KTOT + k) * 4;
        atomicAdd(pc + 0, accC.x); atomicAdd(pc + 1, accC.y);
        atomicAdd(pc + 2, accC.z); atomicAdd(pc + 3, accC.w);
        float* ps = Ss + (size_t)(b * KTOT + k) * 4;
        atomicAdd(ps + 0, accS.x); atomicAdd(ps + 1, accS.y);
        atomicAdd(ps + 2, accS.z); atomicAdd(ps + 3, accS.w);
    }
}

// ---------------- Kernel C: per-atom potential via i-plane recurrences ----------------
__global__ __launch_bounds__(256) void kPot(
    const float* __restrict__ frac2pi, const float* __restrict__ source,
    const int* __restrict__ start, const float* __restrict__ wbuf,
    const float* __restrict__ Sc, const float* __restrict__ Ss,
    float* __restrict__ out)
{
    __shared__ float  lw[81];
    __shared__ float4 lSc[81];
    __shared__ float4 lSs[81];

    int b = blockIdx.x;
    int p = blockIdx.y;     // plane index 0..8 -> i = p-4
    int tid = threadIdx.x;

    if (tid < 81) {
        int idx = p * 81 + tid;
        if (idx == 364) {   // the excluded k=0 point
            lw[tid] = 0.f;
            lSc[tid] = make_float4(0.f, 0.f, 0.f, 0.f);
            lSs[tid] = make_float4(0.f, 0.f, 0.f, 0.f);
        } else {
            int k = idx - (idx > 364 ? 1 : 0);
            lw[tid]  = wbuf[b * KTOT + k];
            lSc[tid] = ((const float4*)Sc)[b * KTOT + k];
            lSs[tid] = ((const float4*)Ss)[b * KTOT + k];
        }
    }
    __syncthreads();

    int s0 = start[b], e0 = start[b + 1];
    float fi = (float)(p - 4);

    for (int n = s0 + tid; n < e0; n += 256) {
        float p1 = frac2pi[n * 3 + 0];
        float p2 = frac2pi[n * 3 + 1];
        float p3 = frac2pi[n * 3 + 2];
        float4 s = ((const float4*)source)[n];

        float si0, ci0; sincosf(fi * p1, &si0, &ci0);
        float s2, c2;   sincosf(p2, &s2, &c2);
        float s3, c3;   sincosf(p3, &s3, &c3);

        float c2_2 = c2 * c2 - s2 * s2, s2_2 = 2.f * c2 * s2;
        float c2_4 = c2_2 * c2_2 - s2_2 * s2_2, s2_4 = 2.f * c2_2 * s2_2;
        float c3_2 = c3 * c3 - s3 * s3, s3_2 = 2.f * c3 * s3;
        float c3_4 = c3_2 * c3_2 - s3_2 * s3_2, s3_4 = 2.f * c3_2 * s3_2;

        // ej = rot(i*p1) * rot(-4*p2)
        float ejc = ci0 * c2_4 + si0 * s2_4;
        float ejs = si0 * c2_4 - ci0 * s2_4;

        float acc = 0.f;
        for (int jj = 0; jj < 9; ++jj) {
            // f = ej * rot(-4*p3)
            float fc = ejc * c3_4 + ejs * s3_4;
            float fs = ejs * c3_4 - ejc * s3_4;
            #pragma unroll
            for (int ll = 0; ll < 9; ++ll) {
                int e = jj * 9 + ll;
                float4 C  = lSc[e];
                float4 S4 = lSs[e];
                float w = lw[e];
                float dc = s.x * C.x  + s.y * C.y  + s.z * C.z  + s.w * C.w;
                float ds = s.x * S4.x + s.y * S4.y + s.z * S4.z + s.w * S4.w;
                acc = fmaf(w, fmaf(fc, dc, fs * ds), acc);
                float nfc = fc * c3 - fs * s3;
                fs = fc * s3 + fs * c3;
                fc = nfc;
            }
            float nejc = ejc * c2 - ejs * s2;
            ejs = ejc * s2 + ejs * c2;
            ejc = nejc;
        }
        atomicAdd(&out[n], acc);
    }
}

extern "C" void kernel_launch(void* const* d_in, const int* in_sizes, int n_in,
                              void* d_out, int out_size, void* d_ws, size_t ws_size,
                              hipStream_t stream)
{
    const float* pos    = (const float*)d_in[0];
    const int*   batch  = (const int*)d_in[1];
    const float* cell   = (const float*)d_in[2];
    const float* source = (const float*)d_in[3];
    const float* W1 = (const float*)d_in[4];
    const float* b1 = (const float*)d_in[5];
    const float* W2 = (const float*)d_in[6];
    const float* b2 = (const float*)d_in[7];
    const float* W3 = (const float*)d_in[8];
    const float* b3 = (const float*)d_in[9];
    float* out = (float*)d_out;

    float* ws   = (float*)d_ws;
    float* inv  = ws;                 // 32*9   = 288
    float* wbuf = ws + 288;           // 32*728 = 23296
    float* frac = ws + 23584;         // 8192*3 = 24576
    float* Sc   = ws + 48160;         // 32*728*4 = 93184 (16B aligned)
    float* Ss   = ws + 141344;        // 93184
    int* startp = (int*)(ws + 234528);// 33 ints

    (void)hipMemsetAsync(Sc, 0, (size_t)2 * 93184 * sizeof(float), stream);
    (void)hipMemsetAsync(out, 0, (size_t)N_ATOMS * sizeof(float), stream);

    kStart<<<1, 64, 0, stream>>>(batch, startp);
    kA<<<dim3(NGRAPH, 3), 256, 0, stream>>>(cell, W1, b1, W2, b2, W3, b3, inv, wbuf);
    kFrac<<<dim3(N_ATOMS / 256), 256, 0, stream>>>(pos, batch, inv, frac);
    kS<<<dim3(NGRAPH, 3, 4), 256, 0, stream>>>(frac, source, startp, Sc, Ss);
    kPot<<<dim3(NGRAPH, 9), 256, 0, stream>>>(frac, source, startp, wbuf, Sc, Ss, out);
}

// Round 3
// 139.298 us; speedup vs baseline: 1.0562x; 1.0562x over previous
//
#include <hip/hip_runtime.h>
#include <math.h>

#define N_ATOMS 8192
#define NGRAPH  32
#define HDIM    64
#define KTOT    728
#define TWO_PI  6.28318530717958647692f

__device__ __forceinline__ float silu_f(float x) {
    return x / (1.0f + expf(-x));
}

__device__ __forceinline__ int lower_bound_batch(const int* __restrict__ batch, int v) {
    int lo = 0, hi = N_ATOMS;
    while (lo < hi) {
        int mid = (lo + hi) >> 1;
        if (batch[mid] < v) lo = mid + 1; else hi = mid;
    }
    return lo;
}

// ---------------- K1: fused MLP weights + frac coords + buffer zeroing ----------------
__global__ __launch_bounds__(256) void kPrep(
    const float* __restrict__ cell, const float* __restrict__ pos,
    const int* __restrict__ batch,
    const float* __restrict__ W1, const float* __restrict__ b1,
    const float* __restrict__ W2, const float* __restrict__ b2,
    const float* __restrict__ W3, const float* __restrict__ b3,
    float* __restrict__ wout, float* __restrict__ frac2pi,
    float* __restrict__ Sc, float* __restrict__ Ss, float* __restrict__ out)
{
    int b = blockIdx.x;
    int y = blockIdx.y;
    int tid = threadIdx.x;
    int gt = (b * 3 + y) * 256 + tid;     // 0..24575 global thread id

    // ---- zero Sc/Ss (23296 float4 each) and out (2048 float4) ----
    const float4 z4 = make_float4(0.f, 0.f, 0.f, 0.f);
    if (gt < 23296) {
        ((float4*)Sc)[gt] = z4;
        ((float4*)Ss)[gt] = z4;
    }
    if (gt < 2048) ((float4*)out)[gt] = z4;

    // ---- fractional coords (y==0 blocks cover all 8192 atoms) ----
    if (y == 0) {
        int n = b * 256 + tid;
        int bn = batch[n];
        const float* cn = cell + bn * 9;
        float a00 = cn[0], a01 = cn[1], a02 = cn[2];
        float a10 = cn[3], a11 = cn[4], a12 = cn[5];
        float a20 = cn[6], a21 = cn[7], a22 = cn[8];
        float c00 = a11 * a22 - a12 * a21;
        float c01 = a12 * a20 - a10 * a22;
        float c02 = a10 * a21 - a11 * a20;
        float det = a00 * c00 + a01 * c01 + a02 * c02;
        float rdet = 1.0f / det;
        float i00 = c00 * rdet;
        float i01 = (a02 * a21 - a01 * a22) * rdet;
        float i02 = (a01 * a12 - a02 * a11) * rdet;
        float i10 = c01 * rdet;
        float i11 = (a00 * a22 - a02 * a20) * rdet;
        float i12 = (a02 * a10 - a00 * a12) * rdet;
        float i20 = c02 * rdet;
        float i21 = (a01 * a20 - a00 * a21) * rdet;
        float i22 = (a00 * a11 - a01 * a10) * rdet;
        float px = pos[n * 3], py = pos[n * 3 + 1], pz = pos[n * 3 + 2];
        frac2pi[n * 3 + 0] = TWO_PI * (px * i00 + py * i10 + pz * i20);
        frac2pi[n * 3 + 1] = TWO_PI * (px * i01 + py * i11 + pz * i21);
        frac2pi[n * 3 + 2] = TWO_PI * (px * i02 + py * i12 + pz * i22);
    }

    // ---- per-k MLP weight for graph b ----
    int k = y * 256 + tid;
    if (k >= KTOT) return;

    const float* cb = cell + b * 9;
    float a00 = cb[0], a01 = cb[1], a02 = cb[2];
    float a10 = cb[3], a11 = cb[4], a12 = cb[5];
    float a20 = cb[6], a21 = cb[7], a22 = cb[8];
    float c00 = a11 * a22 - a12 * a21;
    float c01 = a12 * a20 - a10 * a22;
    float c02 = a10 * a21 - a11 * a20;
    float det = a00 * c00 + a01 * c01 + a02 * c02;
    float vol = fmaxf(fabsf(det), 1e-6f);
    float rdet = 1.0f / det;
    float inv00 = c00 * rdet;
    float inv01 = (a02 * a21 - a01 * a22) * rdet;
    float inv02 = (a01 * a12 - a02 * a11) * rdet;
    float inv10 = c01 * rdet;
    float inv11 = (a00 * a22 - a02 * a20) * rdet;
    float inv12 = (a02 * a10 - a00 * a12) * rdet;
    float inv20 = c02 * rdet;
    float inv21 = (a01 * a20 - a00 * a21) * rdet;
    float inv22 = (a00 * a11 - a01 * a10) * rdet;

    int idx = (k < 364) ? k : k + 1;   // skip (0,0,0)
    float fi = (float)(idx / 81 - 4);
    float fj = (float)((idx / 9) % 9 - 4);
    float fl = (float)(idx % 9 - 4);

    float kx = TWO_PI * (fi * inv00 + fj * inv10 + fl * inv20);
    float ky = TWO_PI * (fi * inv01 + fj * inv11 + fl * inv21);
    float kz = TWO_PI * (fi * inv02 + fj * inv12 + fl * inv22);
    float kn = sqrtf(kx * kx + ky * ky + kz * kz);
    float sk = fmaxf(kn, 1e-6f);

    float x0 = log1pf(sk);
    float f0 = x0, f1 = x0 * x0, f2 = 1.0f / sk;

    float h1v[HDIM];
    #pragma unroll
    for (int j = 0; j < HDIM; ++j) {
        float a = b1[j] + f0 * W1[j] + f1 * W1[64 + j] + f2 * W1[128 + j];
        h1v[j] = silu_f(a);
    }

    float mlp = b3[0];
    for (int half = 0; half < 2; ++half) {
        float acc[32];
        #pragma unroll
        for (int j = 0; j < 32; ++j) acc[j] = b2[half * 32 + j];
        for (int i = 0; i < HDIM; ++i) {
            float h = h1v[i];
            const float* w2row = W2 + i * 64 + half * 32;
            #pragma unroll
            for (int j = 0; j < 32; ++j) acc[j] = fmaf(h, w2row[j], acc[j]);
        }
        #pragma unroll
        for (int j = 0; j < 32; ++j) mlp += silu_f(acc[j]) * W3[half * 32 + j];
    }

    float sc = (mlp > 20.0f) ? mlp : log1pf(expf(mlp));
    float w = (12.566370614359172954f / (sk * sk)) * sc;   // 4*pi/k^2 * scale
    if (!(kn > 1e-6f)) w = 0.0f;
    wout[b * KTOT + k] = w / (2.0f * vol);                 // fold 0.5/vol
}

// ---------------- K2: structure factors ----------------
#define CHUNK 64
__global__ __launch_bounds__(256) void kS(
    const float* __restrict__ frac2pi, const float* __restrict__ source,
    const int* __restrict__ batch,
    float* __restrict__ Sc, float* __restrict__ Ss)
{
    __shared__ float2 tab[CHUNK][3][9];   // cos/sin(m * p_d), m in [-4,4]
    __shared__ float4 srcs[CHUNK];

    int b = blockIdx.x;
    int tid = threadIdx.x;
    int k = blockIdx.y * 256 + tid;

    int s0 = lower_bound_batch(batch, b);
    int e0 = lower_bound_batch(batch, b + 1);
    int len = e0 - s0;
    int per = (len + 3) >> 2;             // gridDim.z == 4 atom slices
    int nb = s0 + blockIdx.z * per;
    int ne = min(nb + per, e0);

    bool active = (k < KTOT);
    int kk = active ? k : 0;
    int idx = (kk < 364) ? kk : kk + 1;
    int ip4 = idx / 81;
    int jp4 = (idx / 9) % 9;
    int lp4 = idx % 9;

    float4 accC = make_float4(0.f, 0.f, 0.f, 0.f);
    float4 accS = make_float4(0.f, 0.f, 0.f, 0.f);

    for (int base = nb; base < ne; base += CHUNK) {
        int cnt = min(CHUNK, ne - base);
        __syncthreads();
        if (tid < 192) {
            int a = tid & 63, d = tid >> 6;
            if (a < cnt) {
                float p = frac2pi[(base + a) * 3 + d];
                float s1, c1; sincosf(p, &s1, &c1);
                float c2 = c1 * c1 - s1 * s1, s2 = 2.f * c1 * s1;
                float c3 = c2 * c1 - s2 * s1, s3 = c2 * s1 + s2 * c1;
                float c4 = c2 * c2 - s2 * s2, s4 = 2.f * c2 * s2;
                tab[a][d][4] = make_float2(1.f, 0.f);
                tab[a][d][5] = make_float2(c1, s1);
                tab[a][d][3] = make_float2(c1, -s1);
                tab[a][d][6] = make_float2(c2, s2);
                tab[a][d][2] = make_float2(c2, -s2);
                tab[a][d][7] = make_float2(c3, s3);
                tab[a][d][1] = make_float2(c3, -s3);
                tab[a][d][8] = make_float2(c4, s4);
                tab[a][d][0] = make_float2(c4, -s4);
            }
        } else {
            int a = tid - 192;
            if (a < cnt) srcs[a] = ((const float4*)source)[base + a];
        }
        __syncthreads();

        if (active) {
            for (int a = 0; a < cnt; ++a) {
                float2 ti = tab[a][0][ip4];
                float2 tj = tab[a][1][jp4];
                float2 tl = tab[a][2][lp4];
                float c12 = ti.x * tj.x - ti.y * tj.y;
                float s12 = ti.x * tj.y + ti.y * tj.x;
                float cv = c12 * tl.x - s12 * tl.y;
                float sv = c12 * tl.y + s12 * tl.x;
                float4 s = srcs[a];
                accC.x = fmaf(s.x, cv, accC.x); accC.y = fmaf(s.y, cv, accC.y);
                accC.z = fmaf(s.z, cv, accC.z); accC.w = fmaf(s.w, cv, accC.w);
                accS.x = fmaf(s.x, sv, accS.x); accS.y = fmaf(s.y, sv, accS.y);
                accS.z = fmaf(s.z, sv, accS.z); accS.w = fmaf(s.w, sv, accS.w);
            }
        }
    }

    if (active) {
        float* pc = Sc + (size_t)(b * KTOT + k) * 4;
        atomicAdd(pc + 0, accC.x); atomicAdd(pc + 1, accC.y);
        atomicAdd(pc + 2, accC.z); atomicAdd(pc + 3, accC.w);
        float* ps = Ss + (size_t)(b * KTOT + k) * 4;
        atomicAdd(ps + 0, accS.x); atomicAdd(ps + 1, accS.y);
        atomicAdd(ps + 2, accS.z); atomicAdd(ps + 3, accS.w);
    }
}

// ---------------- K3: per-atom potential via i-plane recurrences ----------------
__global__ __launch_bounds__(256) void kPot(
    const float* __restrict__ frac2pi, const float* __restrict__ source,
    const int* __restrict__ batch, const float* __restrict__ wbuf,
    const float* __restrict__ Sc, const float* __restrict__ Ss,
    float* __restrict__ out)
{
    __shared__ float  lw[81];
    __shared__ float4 lSc[81];
    __shared__ float4 lSs[81];

    int b = blockIdx.x;
    int p = blockIdx.y;     // plane index 0..8 -> i = p-4
    int tid = threadIdx.x;

    if (tid < 81) {
        int idx = p * 81 + tid;
        if (idx == 364) {   // excluded k=0 point
            lw[tid] = 0.f;
            lSc[tid] = make_float4(0.f, 0.f, 0.f, 0.f);
            lSs[tid] = make_float4(0.f, 0.f, 0.f, 0.f);
        } else {
            int k = idx - (idx > 364 ? 1 : 0);
            lw[tid]  = wbuf[b * KTOT + k];
            lSc[tid] = ((const float4*)Sc)[b * KTOT + k];
            lSs[tid] = ((const float4*)Ss)[b * KTOT + k];
        }
    }
    __syncthreads();

    int s0 = lower_bound_batch(batch, b);
    int e0 = lower_bound_batch(batch, b + 1);
    float fi = (float)(p - 4);

    for (int n = s0 + tid; n < e0; n += 256) {
        float p1 = frac2pi[n * 3 + 0];
        float p2 = frac2pi[n * 3 + 1];
        float p3 = frac2pi[n * 3 + 2];
        float4 s = ((const float4*)source)[n];

        float si0, ci0; sincosf(fi * p1, &si0, &ci0);
        float s2, c2;   sincosf(p2, &s2, &c2);
        float s3, c3;   sincosf(p3, &s3, &c3);

        float c2_2 = c2 * c2 - s2 * s2, s2_2 = 2.f * c2 * s2;
        float c2_4 = c2_2 * c2_2 - s2_2 * s2_2, s2_4 = 2.f * c2_2 * s2_2;
        float c3_2 = c3 * c3 - s3 * s3, s3_2 = 2.f * c3 * s3;
        float c3_4 = c3_2 * c3_2 - s3_2 * s3_2, s3_4 = 2.f * c3_2 * s3_2;

        float ejc = ci0 * c2_4 + si0 * s2_4;   // rot(i*p1) * rot(-4*p2)
        float ejs = si0 * c2_4 - ci0 * s2_4;

        float acc = 0.f;
        for (int jj = 0; jj < 9; ++jj) {
            float fc = ejc * c3_4 + ejs * s3_4;   // ej * rot(-4*p3)
            float fs = ejs * c3_4 - ejc * s3_4;
            #pragma unroll
            for (int ll = 0; ll < 9; ++ll) {
                int e = jj * 9 + ll;
                float4 C  = lSc[e];
                float4 S4 = lSs[e];
                float w = lw[e];
                float dc = s.x * C.x  + s.y * C.y  + s.z * C.z  + s.w * C.w;
                float ds = s.x * S4.x + s.y * S4.y + s.z * S4.z + s.w * S4.w;
                acc = fmaf(w, fmaf(fc, dc, fs * ds), acc);
                float nfc = fc * c3 - fs * s3;
                fs = fc * s3 + fs * c3;
                fc = nfc;
            }
            float nejc = ejc * c2 - ejs * s2;
            ejs = ejc * s2 + ejs * c2;
            ejc = nejc;
        }
        atomicAdd(&out[n], acc);
    }
}

extern "C" void kernel_launch(void* const* d_in, const int* in_sizes, int n_in,
                              void* d_out, int out_size, void* d_ws, size_t ws_size,
                              hipStream_t stream)
{
    const float* pos    = (const float*)d_in[0];
    const int*   batch  = (const int*)d_in[1];
    const float* cell   = (const float*)d_in[2];
    const float* source = (const float*)d_in[3];
    const float* W1 = (const float*)d_in[4];
    const float* b1 = (const float*)d_in[5];
    const float* W2 = (const float*)d_in[6];
    const float* b2 = (const float*)d_in[7];
    const float* W3 = (const float*)d_in[8];
    const float* b3 = (const float*)d_in[9];
    float* out = (float*)d_out;

    float* ws   = (float*)d_ws;
    float* wbuf = ws;                  // 32*728   = 23296 floats
    float* frac = ws + 23296;          // 8192*3   = 24576 floats
    float* Sc   = ws + 47872;          // 32*728*4 = 93184 floats (16B aligned)
    float* Ss   = ws + 141056;         // 93184 floats

    kPrep<<<dim3(NGRAPH, 3), 256, 0, stream>>>(cell, pos, batch,
        W1, b1, W2, b2, W3, b3, wbuf, frac, Sc, Ss, out);
    kS<<<dim3(NGRAPH, 3, 4), 256, 0, stream>>>(frac, source, batch, Sc, Ss);
    kPot<<<dim3(NGRAPH, 9), 256, 0, stream>>>(frac, source, batch, wbuf, Sc, Ss, out);
}